// Round 5
// baseline (513.005 us; speedup 1.0000x reference)
//
#include <hip/hip_runtime.h>
#include <hip/hip_cooperative_groups.h>

namespace cg = cooperative_groups;

#define NCELL 24576      // 128*192 feature cells
#define NTOT  221184     // NCELL * 9
#define NBIN  65536
#define TOPN  6000
#define POSTN 300
#define CAP   8192       // compaction capacity
#define NPADR 6016       // padded candidate count (94 words of 64)
#define NW    94         // suppression-mask words per row
#define CHUNK_W 8        // words per scan chunk (512 ranks)
#define NCHUNK 12        // ceil(94/8)
#define NBLK  256
#define NTHR  256

// Single cooperative kernel: decode -> thresh -> compact -> rank+scatter ->
// matrix -> greedy scan. 6 grid syncs replace 8 kernel-launch gaps.
__global__ __launch_bounds__(NTHR) void fused_kernel(
    const float* __restrict__ scores,
    const float* __restrict__ deltas,
    const float* __restrict__ iminfo,
    float4* __restrict__ boxes,
    unsigned* __restrict__ skeys,
    unsigned* __restrict__ hist,
    unsigned* __restrict__ meta,
    unsigned long long* __restrict__ cbuf,
    float4* __restrict__ sortedbox,
    unsigned long long* __restrict__ rowmat,
    float* __restrict__ out)
{
#pragma clang fp contract(off)
    cg::grid_group grid = cg::this_grid();
    const int tid = threadIdx.x;
    const int bid = blockIdx.x;
    const int gtid = bid * NTHR + tid;

    __shared__ __align__(16) unsigned char smem[512 * CHUNK_W * 8];  // 32 KB, multi-purpose
    __shared__ unsigned long long gm[128];
    __shared__ int keptArr[POSTN];
    __shared__ int s_kept;
    __shared__ unsigned sB, sAbove;

    // ---------------- P0: zero hist + meta ----------------
    if (gtid < NBIN) hist[gtid] = 0u;
    if (gtid < 16) meta[gtid] = 0u;
    grid.sync();

    // ---------------- P1: decode + histogram ----------------
    if (gtid < NCELL) {
        const int c = gtid;
        const float AW[9] = {184.f,368.f,736.f,128.f,256.f,512.f, 88.f,176.f,352.f};
        const float AH[9] = { 96.f,192.f,384.f,128.f,256.f,512.f,176.f,352.f,704.f};
        float sx = (float)((c >> 7) << 4);   // (c/128)*16  -- 'ij' meshgrid quirk
        float sy = (float)((c & 127) << 4);  // (c%128)*16
        float imh = iminfo[0], imw = iminfo[1], ims = iminfo[2];
        float xhi = imw - 1.0f, yhi = imh - 1.0f;
        float ms = 16.0f * ims;
        float ctrx = sx + 8.0f, ctry = sy + 8.0f;
        const float* sbase = scores + 9 * NCELL + c;
        const float* dbase = deltas + c;
#pragma unroll
        for (int a = 0; a < 9; ++a) {
            float sc = sbase[a * NCELL];
            float dx = dbase[(4 * a + 0) * NCELL];
            float dy = dbase[(4 * a + 1) * NCELL];
            float dw = dbase[(4 * a + 2) * NCELL];
            float dh = dbase[(4 * a + 3) * NCELL];
            float pcx = dx * AW[a] + ctrx;
            float pcy = dy * AH[a] + ctry;
            float pw = expf(dw) * AW[a];
            float ph = expf(dh) * AH[a];
            float x1 = pcx - 0.5f * pw;
            float y1 = pcy - 0.5f * ph;
            float x2 = pcx + 0.5f * pw;
            float y2 = pcy + 0.5f * ph;
            x1 = fminf(fmaxf(x1, 0.0f), xhi);
            x2 = fminf(fmaxf(x2, 0.0f), xhi);
            y1 = fminf(fmaxf(y1, 0.0f), yhi);
            y2 = fminf(fmaxf(y2, 0.0f), yhi);
            bool valid = ((x2 - x1 + 1.0f) >= ms) && ((y2 - y1 + 1.0f) >= ms);
            unsigned u = __float_as_uint(sc);
            unsigned key = (u & 0x80000000u) ? ~u : (u | 0x80000000u);
            if (!valid) key = 0x007FFFFFu;   // sort key of -inf
            boxes[a * NCELL + c] = make_float4(x1, y1, x2, y2);
            skeys[a * NCELL + c] = key;
            atomicAdd(&hist[key >> 16], 1u);
        }
    }
    grid.sync();

    // ---------------- P2: threshold bin T (block 0) ----------------
    if (bid == 0) {
        unsigned* csum = (unsigned*)smem;
        const uint4* h4 = (const uint4*)hist;
        unsigned s = 0;
#pragma unroll 8
        for (int q = 0; q < 64; ++q) {
            uint4 u = h4[tid * 64 + q];
            s += u.x + u.y + u.z + u.w;
        }
        csum[tid] = s;
        __syncthreads();
        if (tid < 64) {
            int lane = tid;
            unsigned c0 = csum[lane * 4 + 0], c1 = csum[lane * 4 + 1];
            unsigned c2 = csum[lane * 4 + 2], c3 = csum[lane * 4 + 3];
            unsigned ls = c0 + c1 + c2 + c3;
            unsigned v = ls;
#pragma unroll
            for (int o = 1; o < 64; o <<= 1) {
                unsigned t = __shfl_down(v, o, 64);
                if (lane + o < 64) v += t;
            }
            unsigned sufExcl = v - ls;
            unsigned a3 = sufExcl;
            unsigned a2 = a3 + c3;
            unsigned a1 = a2 + c2;
            unsigned a0 = a1 + c1;
            if (a0 < TOPN && a0 + c0 >= TOPN) { sB = lane * 4 + 0; sAbove = a0; }
            if (a1 < TOPN && a1 + c1 >= TOPN) { sB = lane * 4 + 1; sAbove = a1; }
            if (a2 < TOPN && a2 + c2 >= TOPN) { sB = lane * 4 + 2; sAbove = a2; }
            if (a3 < TOPN && a3 + c3 >= TOPN) { sB = lane * 4 + 3; sAbove = a3; }
        }
        __syncthreads();
        if (tid < 64) {
            int lane = tid;
            unsigned B = sB, above = sAbove;
            uint4 f = h4[B * 64 + lane];
            unsigned ls = f.x + f.y + f.z + f.w;
            unsigned v = ls;
#pragma unroll
            for (int o = 1; o < 64; o <<= 1) {
                unsigned t = __shfl_down(v, o, 64);
                if (lane + o < 64) v += t;
            }
            unsigned sufExcl = v - ls;
            unsigned b3 = above + sufExcl;
            unsigned b2 = b3 + f.w;
            unsigned b1 = b2 + f.z;
            unsigned b0 = b1 + f.y;
            unsigned base2 = B * 256 + lane * 4;
            if (b0 < TOPN && b0 + f.x >= TOPN) meta[1] = base2 + 0;
            if (b1 < TOPN && b1 + f.y >= TOPN) meta[1] = base2 + 1;
            if (b2 < TOPN && b2 + f.z >= TOPN) meta[1] = base2 + 2;
            if (b3 < TOPN && b3 + f.w >= TOPN) meta[1] = base2 + 3;
        }
        __threadfence();
    }
    grid.sync();

    // ---------------- P3: compact candidates with key_hi >= T ----------------
    {
        unsigned T = meta[1];
        for (int m = gtid; m < NTOT; m += NBLK * NTHR) {
            unsigned sk = skeys[m];
            if ((sk >> 16) >= T) {
                unsigned pos = atomicAdd(&meta[0], 1u);
                if (pos < CAP) {
                    unsigned n = (unsigned)((m % NCELL) * 9 + (m / NCELL));
                    cbuf[pos] = ((unsigned long long)sk << 32) | (unsigned long long)(~n);
                }
            }
        }
    }
    grid.sync();

    // ---------------- P4: rank by counting + scatter (atomic-free) ----------------
    {
        unsigned long long* jk = (unsigned long long*)smem;        // 4 KB
        unsigned* partial = (unsigned*)(smem + 4096);              // 1 KB
        unsigned count = meta[0];
        if (count > (unsigned)CAP) count = CAP;
        int i0 = bid * 32;                      // 32 ranks per block
        int myi = i0 + (tid >> 3);              // 8 threads per i
        int slice = tid & 7;                    // j-slice within 512-tile
        unsigned long long ki = (myi < (int)count) ? cbuf[myi] : ~0ULL;
        unsigned cr = 0;
        for (int jt = 0; jt < 16; ++jt) {
            __syncthreads();
            for (int q = tid; q < 512; q += NTHR) {
                int j = (jt << 9) + q;
                jk[q] = (j < (int)count) ? cbuf[j] : 0ULL;   // 0 never > any real key
            }
            __syncthreads();
            const unsigned long long* jp = jk + (slice << 6);
#pragma unroll 8
            for (int j = 0; j < 64; ++j) cr += (jp[j] > ki) ? 1u : 0u;
        }
        partial[tid] = cr;
        __syncthreads();
        if (tid < 32) {
            int i = i0 + tid;
            if (i < (int)count) {
                unsigned r = 0;
#pragma unroll
                for (int q = 0; q < 8; ++q) r += partial[(tid << 3) + q];
                if (r < NPADR) {
                    unsigned n = ~(unsigned)cbuf[i];
                    unsigned m = (n % 9u) * (unsigned)NCELL + (n / 9u);
                    sortedbox[r] = boxes[m];
                }
            }
        }
    }
    grid.sync();

    // ---------------- P5: all-pairs suppression matrix ----------------
    {
        float4* rb = (float4*)smem;             // 256 B
        float*  ra = (float*)(smem + 256);      // 64 B
        for (int tile = bid; tile < NPADR / 16; tile += NBLK) {
            int r0 = tile * 16;
            __syncthreads();
            if (tid < 16) {
                float4 v = sortedbox[r0 + tid];
                rb[tid] = v;
                ra[tid] = (v.z - v.x) * (v.w - v.y);
            }
            __syncthreads();
            int wave = tid >> 6, lane = tid & 63;
            for (int w = wave; w < NW; w += 4) {
                int j = (w << 6) + lane;
                float4 cb = sortedbox[j];
                float ca = (cb.z - cb.x) * (cb.w - cb.y);
#pragma unroll 4
                for (int rr = 0; rr < 16; ++rr) {
                    int i = r0 + rr;
                    if (((w << 6) + 63) <= i) {
                        if (lane == 0) rowmat[(size_t)i * NW + w] = 0ULL;
                        continue;
                    }
                    float4 bi = rb[rr];
                    float ai = ra[rr];
                    float iw = fminf(bi.z, cb.z) - fmaxf(bi.x, cb.x);
                    float ih = fminf(bi.w, cb.w) - fmaxf(bi.y, cb.y);
                    iw = fmaxf(iw, 0.0f);
                    ih = fmaxf(ih, 0.0f);
                    float inter = iw * ih;
                    float denom = fmaxf(ai + ca - inter, 1e-9f);
                    bool sup = (j > i) && (inter / denom > 0.7f);
                    unsigned long long word = __ballot(sup);
                    if (lane == 0) rowmat[(size_t)i * NW + w] = word;
                }
            }
        }
    }
    grid.sync();

    // ---------------- P6: chunked greedy scan (block 0) + output ----------------
    if (bid == 0) {
        unsigned long long* diag = (unsigned long long*)smem;   // 32 KB
        if (tid < 128) gm[tid] = (tid == 93) ? ~((1ULL << 48) - 1) : 0ULL; // ranks>=6000 dead
        if (tid == 0) s_kept = 0;
        for (int e = tid; e < 512 * CHUNK_W; e += NTHR) {
            int r = e >> 3, wl = e & 7;
            diag[e] = rowmat[(size_t)r * NW + wl];
        }
        __syncthreads();

        int keptPrev = 0;
        for (int c = 0; c < NCHUNK; ++c) {
            int wbase = c * CHUNK_W;
            int nwords = NW - wbase; if (nwords > CHUNK_W) nwords = CHUNK_W;
            int rbase = wbase << 6;
            // resolve this chunk (wave 0): ballot-based find, LDS row apply
            if (tid < 64) {
                unsigned long long lv = (tid < nwords) ? ~gm[wbase + tid] : 0ULL;
                int keptLocal = s_kept;
                while (keptLocal < POSTN) {
                    unsigned long long ball = __ballot(lv != 0ULL);
                    if (!ball) break;
                    int wl = __ffsll(ball) - 1;
                    unsigned long long wv = __shfl(lv, wl, 64);
                    int b = __ffsll(wv) - 1;
                    int pos = (wl << 6) + b;
                    if (tid == 0) keptArr[keptLocal] = rbase + pos;
                    keptLocal++;
                    unsigned long long rw = (tid < nwords) ? diag[(pos << 3) + tid] : 0ULL;
                    lv &= ~rw;
                    if (tid == wl) lv &= ~(1ULL << b);
                }
                if (tid == 0) s_kept = keptLocal;
            }
            __syncthreads();
            int keptNow = s_kept;
            bool done = (keptNow >= POSTN) || (c == NCHUNK - 1);
            if (!done) {
                // prefetch next chunk's diag block
                int wb2 = wbase + CHUNK_W;
                int nw2 = NW - wb2; if (nw2 > CHUNK_W) nw2 = CHUNK_W;
                int rb2 = wb2 << 6;
                for (int e = tid; e < 512 * CHUNK_W; e += NTHR) {
                    int r = e >> 3, wl = e & 7;
                    diag[e] = (wl < nw2) ? rowmat[(size_t)(rb2 + r) * NW + wb2 + wl] : 0ULL;
                }
                // propagate kept rows' future words into gm (all 4 waves)
                int lane = tid & 63, q = tid >> 6;
                int wA = wb2 + lane;
                int wB = wA + 64;
                unsigned long long accA = 0ULL, accB = 0ULL;
                for (int s = keptPrev + q; s < keptNow; s += 4) {
                    size_t ro = (size_t)keptArr[s] * NW;
                    if (wA < NW) accA |= rowmat[ro + wA];
                    if (wB < NW) accB |= rowmat[ro + wB];
                }
                if (accA) atomicOr(&gm[wA], accA);
                if (accB) atomicOr(&gm[wB], accB);
            }
            keptPrev = keptNow;
            if (keptNow >= POSTN) break;
            __syncthreads();
        }
        __syncthreads();

        int kept = s_kept;
        for (int k = tid; k < POSTN; k += NTHR) {
            float4 bb = make_float4(0.f, 0.f, 0.f, 0.f);
            if (k < kept) bb = sortedbox[keptArr[k]];
            out[k * 5 + 0] = 0.0f;
            out[k * 5 + 1] = bb.x;
            out[k * 5 + 2] = bb.y;
            out[k * 5 + 3] = bb.z;
            out[k * 5 + 4] = bb.w;
        }
    }
}

extern "C" void kernel_launch(void* const* d_in, const int* in_sizes, int n_in,
                              void* d_out, int out_size, void* d_ws, size_t ws_size,
                              hipStream_t stream) {
    const float* scores = (const float*)d_in[0];
    const float* deltas = (const float*)d_in[1];
    const float* iminfo = (const float*)d_in[2];
    char* w = (char*)d_ws;
    // workspace layout (~4.95 MB). rowmat aliases boxes+skeys (dead after P4).
    float4*   boxes = (float4*)w;                                   // [0, 3538944)
    unsigned* skeys = (unsigned*)(w + 3538944);                     // [3538944, 4423680)
    unsigned long long* rowmat = (unsigned long long*)w;            // [0, 4524032) alias
    unsigned* hist  = (unsigned*)(w + 4524032);                     // [4524032, 4786176)
    unsigned* meta  = (unsigned*)(w + 4786176);                     // 16 words
    unsigned long long* cbuf = (unsigned long long*)(w + 4786240);  // [4786240, 4851776)
    float4* sortedbox = (float4*)(w + 4851776);                     // [4851776, 4948032)
    float* out = (float*)d_out;

    void* args[] = {
        (void*)&scores, (void*)&deltas, (void*)&iminfo, (void*)&boxes,
        (void*)&skeys, (void*)&hist, (void*)&meta, (void*)&cbuf,
        (void*)&sortedbox, (void*)&rowmat, (void*)&out
    };
    hipLaunchCooperativeKernel(reinterpret_cast<void*>(fused_kernel),
                               dim3(NBLK), dim3(NTHR), args, 0, stream);
}

// Round 6
// 315.944 us; speedup vs baseline: 1.6237x; 1.6237x over previous
//
#include <hip/hip_runtime.h>

#define NCELL 24576      // 128*192 feature cells
#define NTOT  221184     // NCELL * 9
#define NBIN  65536
#define TOPN  6000
#define POSTN 300
#define CAP   8192       // compaction capacity
#define NPADR 6016       // padded candidate count (94 words of 64)
#define NW    94         // suppression-mask words per row
#define CW    8          // words per scan chunk (512 ranks)
#define NCHUNK 12        // ceil(94/8)

// ---------------- decode anchors + scores, build sort keys, histogram ----------------
__global__ void decode_kernel(const float* __restrict__ scores,
                              const float* __restrict__ deltas,
                              const float* __restrict__ iminfo,
                              float4* __restrict__ boxes,
                              unsigned* __restrict__ skeys,
                              unsigned* __restrict__ hist) {
#pragma clang fp contract(off)
    int c = blockIdx.x * blockDim.x + threadIdx.x;
    if (c >= NCELL) return;
    const float AW[9] = {184.f,368.f,736.f,128.f,256.f,512.f, 88.f,176.f,352.f};
    const float AH[9] = { 96.f,192.f,384.f,128.f,256.f,512.f,176.f,352.f,704.f};
    float sx = (float)((c >> 7) << 4);   // (c/128)*16  -- 'ij' meshgrid quirk
    float sy = (float)((c & 127) << 4);  // (c%128)*16
    float imh = iminfo[0], imw = iminfo[1], ims = iminfo[2];
    float xhi = imw - 1.0f, yhi = imh - 1.0f;
    float ms = 16.0f * ims;
    float ctrx = sx + 8.0f, ctry = sy + 8.0f;
    const float* sbase = scores + 9 * NCELL + c;
    const float* dbase = deltas + c;
#pragma unroll
    for (int a = 0; a < 9; ++a) {
        float sc = sbase[a * NCELL];
        float dx = dbase[(4 * a + 0) * NCELL];
        float dy = dbase[(4 * a + 1) * NCELL];
        float dw = dbase[(4 * a + 2) * NCELL];
        float dh = dbase[(4 * a + 3) * NCELL];
        float pcx = dx * AW[a] + ctrx;
        float pcy = dy * AH[a] + ctry;
        float pw = expf(dw) * AW[a];
        float ph = expf(dh) * AH[a];
        float x1 = pcx - 0.5f * pw;
        float y1 = pcy - 0.5f * ph;
        float x2 = pcx + 0.5f * pw;
        float y2 = pcy + 0.5f * ph;
        x1 = fminf(fmaxf(x1, 0.0f), xhi);
        x2 = fminf(fmaxf(x2, 0.0f), xhi);
        y1 = fminf(fmaxf(y1, 0.0f), yhi);
        y2 = fminf(fmaxf(y2, 0.0f), yhi);
        bool valid = ((x2 - x1 + 1.0f) >= ms) && ((y2 - y1 + 1.0f) >= ms);
        unsigned u = __float_as_uint(sc);
        unsigned key = (u & 0x80000000u) ? ~u : (u | 0x80000000u);
        if (!valid) key = 0x007FFFFFu;   // sort key of -inf
        boxes[a * NCELL + c] = make_float4(x1, y1, x2, y2);
        skeys[a * NCELL + c] = key;
        atomicAdd(&hist[key >> 16], 1u);
    }
}

// ---------------- find threshold bin T: cum(>T) < 6000 <= cum(>=T) ----------------
__global__ __launch_bounds__(1024) void thresh_kernel(const unsigned* __restrict__ hist,
                                                      unsigned* __restrict__ meta) {
    __shared__ unsigned psum[1024];
    __shared__ unsigned csum[256];
    __shared__ unsigned sB, sAbove;
    int tid = threadIdx.x;
    const uint4* h4 = (const uint4*)hist;
    // coarse bin cb = tid>>2 (256 fine bins = 64 uint4); quarter = tid&3 covers 16 uint4
    unsigned s = 0;
#pragma unroll 4
    for (int q = 0; q < 16; ++q) {
        uint4 u = h4[(tid >> 2) * 64 + (tid & 3) * 16 + q];
        s += u.x + u.y + u.z + u.w;
    }
    psum[tid] = s;
    __syncthreads();
    if (tid < 256)
        csum[tid] = psum[tid * 4] + psum[tid * 4 + 1] + psum[tid * 4 + 2] + psum[tid * 4 + 3];
    __syncthreads();
    if (tid < 64) {
        int lane = tid;
        unsigned c0 = csum[lane * 4 + 0], c1 = csum[lane * 4 + 1];
        unsigned c2 = csum[lane * 4 + 2], c3 = csum[lane * 4 + 3];
        unsigned ls = c0 + c1 + c2 + c3;
        unsigned v = ls;
#pragma unroll
        for (int o = 1; o < 64; o <<= 1) {
            unsigned t = __shfl_down(v, o, 64);
            if (lane + o < 64) v += t;
        }
        unsigned sufExcl = v - ls;   // sum over coarse bins of lanes > lane
        unsigned a3 = sufExcl;
        unsigned a2 = a3 + c3;
        unsigned a1 = a2 + c2;
        unsigned a0 = a1 + c1;
        if (a0 < TOPN && a0 + c0 >= TOPN) { sB = lane * 4 + 0; sAbove = a0; }
        if (a1 < TOPN && a1 + c1 >= TOPN) { sB = lane * 4 + 1; sAbove = a1; }
        if (a2 < TOPN && a2 + c2 >= TOPN) { sB = lane * 4 + 2; sAbove = a2; }
        if (a3 < TOPN && a3 + c3 >= TOPN) { sB = lane * 4 + 3; sAbove = a3; }
    }
    __syncthreads();
    if (tid < 64) {
        int lane = tid;
        unsigned B = sB, above = sAbove;
        uint4 f = h4[B * 64 + lane];       // fine bins B*256 + lane*4 + (0..3)
        unsigned ls = f.x + f.y + f.z + f.w;
        unsigned v = ls;
#pragma unroll
        for (int o = 1; o < 64; o <<= 1) {
            unsigned t = __shfl_down(v, o, 64);
            if (lane + o < 64) v += t;
        }
        unsigned sufExcl = v - ls;
        unsigned b3 = above + sufExcl;
        unsigned b2 = b3 + f.w;
        unsigned b1 = b2 + f.z;
        unsigned b0 = b1 + f.y;
        unsigned base2 = B * 256 + lane * 4;
        if (b0 < TOPN && b0 + f.x >= TOPN) meta[1] = base2 + 0;
        if (b1 < TOPN && b1 + f.y >= TOPN) meta[1] = base2 + 1;
        if (b2 < TOPN && b2 + f.z >= TOPN) meta[1] = base2 + 2;
        if (b3 < TOPN && b3 + f.w >= TOPN) meta[1] = base2 + 3;
    }
}

// ---------------- compact all candidates with key_hi >= T ----------------
__global__ void compact_kernel(const unsigned* __restrict__ skeys,
                               unsigned* __restrict__ meta,
                               unsigned long long* __restrict__ cbuf) {
    int m = blockIdx.x * blockDim.x + threadIdx.x;
    if (m >= NTOT) return;
    unsigned T = meta[1];
    unsigned sk = skeys[m];
    if ((sk >> 16) >= T) {
        unsigned pos = atomicAdd(&meta[0], 1u);
        if (pos < CAP) {
            unsigned n = (unsigned)((m % NCELL) * 9 + (m / NCELL));  // original flat index
            cbuf[pos] = ((unsigned long long)sk << 32) | (unsigned long long)(~n);
        }
    }
}

// ---------------- rank by counting + scatter (atomic-free, no rank array) ----------------
// 256 blocks x 256 thr; 8 threads per rank i (interleaved j-slices -> conflict-free LDS)
__global__ __launch_bounds__(256) void rankscatter_kernel(const unsigned long long* __restrict__ cbuf,
                                                          const unsigned* __restrict__ meta,
                                                          const float4* __restrict__ boxes,
                                                          float4* __restrict__ sortedbox) {
    __shared__ unsigned long long jk[512];
    unsigned count = meta[0];
    if (count > (unsigned)CAP) count = CAP;
    int tid = threadIdx.x;
    int i = blockIdx.x * 32 + (tid >> 3);
    int slice = tid & 7;
    unsigned long long ki = (i < (int)count) ? cbuf[i] : ~0ULL;
    unsigned cr = 0;
    for (int jt = 0; jt < 16; ++jt) {
        __syncthreads();
        for (int q = tid; q < 512; q += 256) {
            int j = (jt << 9) + q;
            jk[q] = (j < (int)count) ? cbuf[j] : 0ULL;   // 0 never > any real key
        }
        __syncthreads();
#pragma unroll 8
        for (int j = 0; j < 64; ++j) cr += (jk[slice + (j << 3)] > ki) ? 1u : 0u;
    }
    cr += __shfl_down(cr, 4, 8);
    cr += __shfl_down(cr, 2, 8);
    cr += __shfl_down(cr, 1, 8);
    if (slice == 0 && i < (int)count && cr < NPADR) {
        unsigned n = ~(unsigned)ki;
        unsigned m = (n % 9u) * (unsigned)NCELL + (n / 9u);
        sortedbox[cr] = boxes[m];
    }
}

// ---------------- all-pairs suppression matrix (dual layout) ----------------
__global__ __launch_bounds__(256) void matrix_kernel(const float4* __restrict__ sortedbox,
                                                     unsigned long long* __restrict__ rowr,
                                                     unsigned long long* __restrict__ roww) {
#pragma clang fp contract(off)
    __shared__ float4 rb[16];
    __shared__ float ra[16];
    int tid = threadIdx.x;
    int r0 = blockIdx.x * 16;
    if (tid < 16) {
        float4 v = sortedbox[r0 + tid];
        rb[tid] = v;
        ra[tid] = (v.z - v.x) * (v.w - v.y);
    }
    __syncthreads();
    int wave = tid >> 6, lane = tid & 63;
    for (int w = wave; w < NW; w += 4) {
        int j = (w << 6) + lane;
        float4 cb = sortedbox[j];
        float ca = (cb.z - cb.x) * (cb.w - cb.y);
#pragma unroll 4
        for (int rr = 0; rr < 16; ++rr) {
            int i = r0 + rr;
            unsigned long long word = 0ULL;
            if (((w << 6) + 63) > i) {
                float4 bi = rb[rr];
                float ai = ra[rr];
                float iw = fminf(bi.z, cb.z) - fmaxf(bi.x, cb.x);
                float ih = fminf(bi.w, cb.w) - fmaxf(bi.y, cb.y);
                iw = fmaxf(iw, 0.0f);
                ih = fmaxf(ih, 0.0f);
                float inter = iw * ih;
                float denom = fmaxf(ai + ca - inter, 1e-9f);
                bool sup = (j > i) && (inter / denom > 0.7f);
                word = __ballot(sup);
            }
            if (lane == 0) {
                rowr[(size_t)i * NW + w] = word;
                roww[(size_t)w * NPADR + i] = word;
            }
        }
    }
}

// ---------------- greedy scan: register/shfl intra-word chain, chunked staging ----------------
__global__ __launch_bounds__(256) void scan_kernel(const unsigned long long* __restrict__ rowr,
                                                   const unsigned long long* __restrict__ roww,
                                                   const float4* __restrict__ sortedbox,
                                                   float* __restrict__ out) {
    __shared__ unsigned long long cblk[CW * 512];   // 32 KB, word-major: cblk[q*512 + r]
    __shared__ int keptArr[POSTN];
    __shared__ int s_kept;
    __shared__ int s_done;
    int tid = threadIdx.x;
    int lane = tid & 63;

    if (tid == 0) { s_kept = 0; s_done = 0; }
    // stage chunk 0 (wbase=0, rbase=0)
    for (int e = tid; e < CW * 512; e += 256) {
        int q = e >> 9, r = e & 511;
        cblk[e] = roww[(size_t)q * NPADR + r];
    }
    __syncthreads();

    unsigned long long m0 = 0ULL, m1 = 0ULL;   // wave-0 global mask: lane holds words lane, 64+lane
    int keptPrev = 0;
    for (int c = 0; c < NCHUNK; ++c) {
        int wbase = c * CW;
        if (tid < 64) {
            // prefetch intra-word diag rows: dg[q] = cblk[q*512 + (q<<6) + lane]
            unsigned long long dg[CW];
#pragma unroll
            for (int q = 0; q < CW; ++q) dg[q] = cblk[(q << 9) + (q << 6) + lane];
            // chunk mask distributed: lane q<CW holds mask word wbase+q
            int wsel = wbase + lane;
            unsigned long long ma = __shfl(m0, wsel & 63, 64);
            unsigned long long mb = __shfl(m1, wsel & 63, 64);
            unsigned long long cm = (lane < CW) ? ((wsel < 64) ? ma : mb) : 0ULL;
            int kept = s_kept;
            int done = 0;
            for (int q = 0; q < CW && wbase + q < NW; ++q) {
                int w = wbase + q;
                unsigned long long live = ~__shfl(cm, q, 64);
                if (w == NW - 1) live &= (1ULL << 48) - 1;   // ranks >= 6000 dead
                unsigned long long kb = 0ULL;
                while (live) {
                    int b = __ffsll((unsigned long long)live) - 1;
                    unsigned long long rowb = __shfl(dg[q], b, 64);
                    kb |= 1ULL << b;
                    live &= ~(rowb | (1ULL << b));
                    kept++;
                    if (kept == POSTN) { done = 1; live = 0ULL; }
                }
                if (kb) {
                    // record kept (ascending bit order = greedy order)
                    if (lane == 0) {
                        unsigned long long t = kb;
                        int k0 = kept - __popcll(kb);
                        while (t) {
                            int b = __ffsll((unsigned long long)t) - 1; t &= t - 1;
                            keptArr[k0++] = (w << 6) + b;
                        }
                    }
                    if (done) break;
                    // apply kept rows' later chunk words to cm (lanes q' > q)
                    unsigned long long t = kb;
                    while (t) {
                        int b = __ffsll((unsigned long long)t) - 1; t &= t - 1;
                        unsigned long long rw = (lane < CW && lane > q)
                            ? cblk[(lane << 9) + (q << 6) + b] : 0ULL;
                        cm |= rw;
                    }
                }
                if (done) break;
            }
            if (lane == 0) { s_kept = kept; if (done) s_done = 1; }
        }
        __syncthreads();
        int keptNow = s_kept;
        bool fin = (s_done != 0) || (c == NCHUNK - 1);
        if (!fin) {
            if (tid >= 64) {
                // stage next chunk (waves 1-3)
                int wb2 = wbase + CW;
                int nw2 = NW - wb2; if (nw2 > CW) nw2 = CW;
                int rb2 = wb2 << 6;
                for (int e = tid - 64; e < CW * 512; e += 192) {
                    int q = e >> 9, r = e & 511;
                    cblk[e] = (q < nw2 && rb2 + r < NPADR)
                        ? roww[(size_t)(wb2 + q) * NPADR + rb2 + r] : 0ULL;
                }
            } else {
                // propagate this chunk's kept rows into m0/m1 (wave 0, coalesced)
                for (int s = keptPrev; s < keptNow; ++s) {
                    size_t ro = (size_t)keptArr[s] * NW;
                    m0 |= rowr[ro + lane];
                    if (lane < NW - 64) m1 |= rowr[ro + 64 + lane];
                }
            }
        }
        keptPrev = keptNow;
        if (fin) break;
        __syncthreads();
    }
    __syncthreads();

    int kept = s_kept;
    for (int k = tid; k < POSTN; k += 256) {
        float4 bb = make_float4(0.f, 0.f, 0.f, 0.f);
        if (k < kept) bb = sortedbox[keptArr[k]];
        out[k * 5 + 0] = 0.0f;
        out[k * 5 + 1] = bb.x;
        out[k * 5 + 2] = bb.y;
        out[k * 5 + 3] = bb.z;
        out[k * 5 + 4] = bb.w;
    }
}

extern "C" void kernel_launch(void* const* d_in, const int* in_sizes, int n_in,
                              void* d_out, int out_size, void* d_ws, size_t ws_size,
                              hipStream_t stream) {
    const float* scores = (const float*)d_in[0];
    const float* deltas = (const float*)d_in[1];
    const float* iminfo = (const float*)d_in[2];
    char* w = (char*)d_ws;
    // workspace layout (~9.5 MB). rowr ALIASES boxes+skeys (both dead after rankscatter).
    float4*   boxes = (float4*)w;                                   // [0, 3538944)
    unsigned* skeys = (unsigned*)(w + 3538944);                     // [3538944, 4423680)
    unsigned long long* rowr = (unsigned long long*)w;              // [0, 4524032) alias
    unsigned* hist  = (unsigned*)(w + 4524032);                     // [4524032, 4786176)
    unsigned* meta  = (unsigned*)(w + 4786176);                     // 16 words
    unsigned long long* cbuf = (unsigned long long*)(w + 4786240);  // [4786240, 4851776)
    float4* sortedbox = (float4*)(w + 4851776);                     // [4851776, 4948032)
    unsigned long long* roww = (unsigned long long*)(w + 4948096);  // [4948096, 9472128)
    float* out = (float*)d_out;

    hipMemsetAsync(hist, 0, NBIN * sizeof(unsigned) + 64, stream);  // hist + meta
    decode_kernel<<<NCELL / 256, 256, 0, stream>>>(scores, deltas, iminfo, boxes, skeys, hist);
    thresh_kernel<<<1, 1024, 0, stream>>>(hist, meta);
    compact_kernel<<<(NTOT + 255) / 256, 256, 0, stream>>>(skeys, meta, cbuf);
    rankscatter_kernel<<<256, 256, 0, stream>>>(cbuf, meta, boxes, sortedbox);
    matrix_kernel<<<NPADR / 16, 256, 0, stream>>>(sortedbox, rowr, roww);
    scan_kernel<<<1, 256, 0, stream>>>(rowr, roww, sortedbox, out);
}

// Round 7
// 267.375 us; speedup vs baseline: 1.9187x; 1.1817x over previous
//
#include <hip/hip_runtime.h>

#define NCELL 24576      // 128*192 feature cells
#define NTOT  221184     // NCELL * 9
#define NBIN  65536
#define TOPN  6000
#define POSTN 300
#define CAP   8192       // compaction capacity
#define NPADR 6016       // padded candidate count (94 words of 64)
#define NW    94         // suppression-mask words per row
#define CW    8          // words per scan chunk (512 ranks)
#define NCHUNK 12        // ceil(94/8)

// ---------------- decode anchors + scores, build sort keys, histogram ----------------
__global__ void decode_kernel(const float* __restrict__ scores,
                              const float* __restrict__ deltas,
                              const float* __restrict__ iminfo,
                              float4* __restrict__ boxes,
                              unsigned* __restrict__ skeys,
                              unsigned* __restrict__ hist) {
#pragma clang fp contract(off)
    int c = blockIdx.x * blockDim.x + threadIdx.x;
    if (c >= NCELL) return;
    const float AW[9] = {184.f,368.f,736.f,128.f,256.f,512.f, 88.f,176.f,352.f};
    const float AH[9] = { 96.f,192.f,384.f,128.f,256.f,512.f,176.f,352.f,704.f};
    float sx = (float)((c >> 7) << 4);   // (c/128)*16  -- 'ij' meshgrid quirk
    float sy = (float)((c & 127) << 4);  // (c%128)*16
    float imh = iminfo[0], imw = iminfo[1], ims = iminfo[2];
    float xhi = imw - 1.0f, yhi = imh - 1.0f;
    float ms = 16.0f * ims;
    float ctrx = sx + 8.0f, ctry = sy + 8.0f;
    const float* sbase = scores + 9 * NCELL + c;
    const float* dbase = deltas + c;
#pragma unroll
    for (int a = 0; a < 9; ++a) {
        float sc = sbase[a * NCELL];
        float dx = dbase[(4 * a + 0) * NCELL];
        float dy = dbase[(4 * a + 1) * NCELL];
        float dw = dbase[(4 * a + 2) * NCELL];
        float dh = dbase[(4 * a + 3) * NCELL];
        float pcx = dx * AW[a] + ctrx;
        float pcy = dy * AH[a] + ctry;
        float pw = expf(dw) * AW[a];
        float ph = expf(dh) * AH[a];
        float x1 = pcx - 0.5f * pw;
        float y1 = pcy - 0.5f * ph;
        float x2 = pcx + 0.5f * pw;
        float y2 = pcy + 0.5f * ph;
        x1 = fminf(fmaxf(x1, 0.0f), xhi);
        x2 = fminf(fmaxf(x2, 0.0f), xhi);
        y1 = fminf(fmaxf(y1, 0.0f), yhi);
        y2 = fminf(fmaxf(y2, 0.0f), yhi);
        bool valid = ((x2 - x1 + 1.0f) >= ms) && ((y2 - y1 + 1.0f) >= ms);
        unsigned u = __float_as_uint(sc);
        unsigned key = (u & 0x80000000u) ? ~u : (u | 0x80000000u);
        if (!valid) key = 0x007FFFFFu;   // sort key of -inf
        boxes[a * NCELL + c] = make_float4(x1, y1, x2, y2);
        skeys[a * NCELL + c] = key;
        atomicAdd(&hist[key >> 16], 1u);
    }
}

// ---------------- find threshold bin T: cum(>T) < 6000 <= cum(>=T) ----------------
__global__ __launch_bounds__(1024) void thresh_kernel(const unsigned* __restrict__ hist,
                                                      unsigned* __restrict__ meta) {
    __shared__ unsigned psum[1024];
    __shared__ unsigned csum[256];
    __shared__ unsigned sB, sAbove;
    int tid = threadIdx.x;
    const uint4* h4 = (const uint4*)hist;
    unsigned s = 0;
#pragma unroll 4
    for (int q = 0; q < 16; ++q) {
        uint4 u = h4[(tid >> 2) * 64 + (tid & 3) * 16 + q];
        s += u.x + u.y + u.z + u.w;
    }
    psum[tid] = s;
    __syncthreads();
    if (tid < 256)
        csum[tid] = psum[tid * 4] + psum[tid * 4 + 1] + psum[tid * 4 + 2] + psum[tid * 4 + 3];
    __syncthreads();
    if (tid < 64) {
        int lane = tid;
        unsigned c0 = csum[lane * 4 + 0], c1 = csum[lane * 4 + 1];
        unsigned c2 = csum[lane * 4 + 2], c3 = csum[lane * 4 + 3];
        unsigned ls = c0 + c1 + c2 + c3;
        unsigned v = ls;
#pragma unroll
        for (int o = 1; o < 64; o <<= 1) {
            unsigned t = __shfl_down(v, o, 64);
            if (lane + o < 64) v += t;
        }
        unsigned sufExcl = v - ls;   // sum over coarse bins of lanes > lane
        unsigned a3 = sufExcl;
        unsigned a2 = a3 + c3;
        unsigned a1 = a2 + c2;
        unsigned a0 = a1 + c1;
        if (a0 < TOPN && a0 + c0 >= TOPN) { sB = lane * 4 + 0; sAbove = a0; }
        if (a1 < TOPN && a1 + c1 >= TOPN) { sB = lane * 4 + 1; sAbove = a1; }
        if (a2 < TOPN && a2 + c2 >= TOPN) { sB = lane * 4 + 2; sAbove = a2; }
        if (a3 < TOPN && a3 + c3 >= TOPN) { sB = lane * 4 + 3; sAbove = a3; }
    }
    __syncthreads();
    if (tid < 64) {
        int lane = tid;
        unsigned B = sB, above = sAbove;
        uint4 f = h4[B * 64 + lane];       // fine bins B*256 + lane*4 + (0..3)
        unsigned ls = f.x + f.y + f.z + f.w;
        unsigned v = ls;
#pragma unroll
        for (int o = 1; o < 64; o <<= 1) {
            unsigned t = __shfl_down(v, o, 64);
            if (lane + o < 64) v += t;
        }
        unsigned sufExcl = v - ls;
        unsigned b3 = above + sufExcl;
        unsigned b2 = b3 + f.w;
        unsigned b1 = b2 + f.z;
        unsigned b0 = b1 + f.y;
        unsigned base2 = B * 256 + lane * 4;
        if (b0 < TOPN && b0 + f.x >= TOPN) meta[1] = base2 + 0;
        if (b1 < TOPN && b1 + f.y >= TOPN) meta[1] = base2 + 1;
        if (b2 < TOPN && b2 + f.z >= TOPN) meta[1] = base2 + 2;
        if (b3 < TOPN && b3 + f.w >= TOPN) meta[1] = base2 + 3;
    }
}

// ---------------- compact all candidates with key_hi >= T ----------------
__global__ void compact_kernel(const unsigned* __restrict__ skeys,
                               unsigned* __restrict__ meta,
                               unsigned long long* __restrict__ cbuf) {
    int m = blockIdx.x * blockDim.x + threadIdx.x;
    if (m >= NTOT) return;
    unsigned T = meta[1];
    unsigned sk = skeys[m];
    if ((sk >> 16) >= T) {
        unsigned pos = atomicAdd(&meta[0], 1u);
        if (pos < CAP) {
            unsigned n = (unsigned)((m % NCELL) * 9 + (m / NCELL));  // original flat index
            cbuf[pos] = ((unsigned long long)sk << 32) | (unsigned long long)(~n);
        }
    }
}

// ---------------- rank by counting + scatter (atomic-free, no rank array) ----------------
__global__ __launch_bounds__(256) void rankscatter_kernel(const unsigned long long* __restrict__ cbuf,
                                                          const unsigned* __restrict__ meta,
                                                          const float4* __restrict__ boxes,
                                                          float4* __restrict__ sortedbox) {
    __shared__ unsigned long long jk[512];
    unsigned count = meta[0];
    if (count > (unsigned)CAP) count = CAP;
    int tid = threadIdx.x;
    int i = blockIdx.x * 32 + (tid >> 3);
    int slice = tid & 7;
    unsigned long long ki = (i < (int)count) ? cbuf[i] : ~0ULL;
    unsigned cr = 0;
    for (int jt = 0; jt < 16; ++jt) {
        if ((jt << 9) >= (int)count) break;    // uniform across block
        __syncthreads();
        for (int q = tid; q < 512; q += 256) {
            int j = (jt << 9) + q;
            jk[q] = (j < (int)count) ? cbuf[j] : 0ULL;   // 0 never > any real key
        }
        __syncthreads();
#pragma unroll 8
        for (int j = 0; j < 64; ++j) cr += (jk[slice + (j << 3)] > ki) ? 1u : 0u;
    }
    cr += __shfl_down(cr, 4, 8);
    cr += __shfl_down(cr, 2, 8);
    cr += __shfl_down(cr, 1, 8);
    if (slice == 0 && i < (int)count && cr < NPADR) {
        unsigned n = ~(unsigned)ki;
        unsigned m = (n % 9u) * (unsigned)NCELL + (n / 9u);
        sortedbox[cr] = boxes[m];
    }
}

// ---------------- all-pairs suppression matrix: word-per-thread ----------------
// grid (24, 94): block = 64 lanes (i) x 4 waves (w). Each thread builds one
// 64-bit word by looping 64 j-boxes from LDS (wave-broadcast reads).
__global__ __launch_bounds__(256) void matrix_kernel(const float4* __restrict__ sortedbox,
                                                     unsigned long long* __restrict__ rowr,
                                                     unsigned long long* __restrict__ diagw) {
#pragma clang fp contract(off)
    __shared__ float4 jb[256];
    __shared__ float  ja[256];
    int tid = threadIdx.x;
    int lane = tid & 63, wave = tid >> 6;
    int i0 = blockIdx.y << 6;
    int i = i0 + lane;
    int w = (blockIdx.x << 2) + wave;
    int jbase = blockIdx.x << 8;
    unsigned long long word = 0ULL;

    if (jbase + 255 > i0) {                  // tile not entirely below diagonal
        int jg = jbase + tid;
        float4 v = (jg < NPADR) ? sortedbox[jg] : make_float4(0.f, 0.f, 0.f, 0.f);
        jb[tid] = v;
        ja[tid] = (v.z - v.x) * (v.w - v.y);
        __syncthreads();
        if (w < NW && ((w << 6) + 63) > i) { // this word has bits above the diagonal
            float4 bi = sortedbox[i];
            float ai = (bi.z - bi.x) * (bi.w - bi.y);
            int jl0 = wave << 6;
            int jg0 = (w << 6);
#pragma unroll 8
            for (int j = 0; j < 64; ++j) {
                float4 bj = jb[jl0 + j];
                float aj = ja[jl0 + j];
                float iw = fminf(bi.z, bj.z) - fmaxf(bi.x, bj.x);
                float ih = fminf(bi.w, bj.w) - fmaxf(bi.y, bj.y);
                iw = fmaxf(iw, 0.0f);
                ih = fmaxf(ih, 0.0f);
                float inter = iw * ih;
                float denom = fmaxf(ai + aj - inter, 1e-9f);
                bool sup = (jg0 + j > i) && (inter / denom > 0.7f);
                word |= (unsigned long long)sup << j;
            }
        }
    }
    if (w < NW) {
        rowr[(size_t)i * NW + w] = word;
        if ((i >> 9) == (w >> 3))            // block-diagonal word -> word-major copy
            diagw[((size_t)w << 9) + (i & 511)] = word;
    }
}

// ---------------- greedy scan: register/shfl intra-word chain, chunked staging ----------------
__global__ __launch_bounds__(256) void scan_kernel(const unsigned long long* __restrict__ rowr,
                                                   const unsigned long long* __restrict__ diagw,
                                                   const float4* __restrict__ sortedbox,
                                                   float* __restrict__ out) {
    __shared__ unsigned long long cblk[CW * 512];   // 32 KB, word-major: cblk[q*512 + r]
    __shared__ int keptArr[POSTN];
    __shared__ int s_kept;
    __shared__ int s_done;
    int tid = threadIdx.x;
    int lane = tid & 63;

    if (tid == 0) { s_kept = 0; s_done = 0; }
    // stage chunk 0 (words 0..7, rows 0..511) -- diagw[0..4096) matches cblk layout
    for (int e = tid; e < CW * 512; e += 256) cblk[e] = diagw[e];
    __syncthreads();

    unsigned long long m0 = 0ULL, m1 = 0ULL;   // wave-0 global mask: lane holds words lane, 64+lane
    int keptPrev = 0;
    for (int c = 0; c < NCHUNK; ++c) {
        int wbase = c * CW;
        if (tid < 64) {
            unsigned long long dg[CW];
#pragma unroll
            for (int q = 0; q < CW; ++q) dg[q] = cblk[(q << 9) + (q << 6) + lane];
            int wsel = wbase + lane;
            unsigned long long ma = __shfl(m0, wsel & 63, 64);
            unsigned long long mb = __shfl(m1, wsel & 63, 64);
            unsigned long long cm = (lane < CW) ? ((wsel < 64) ? ma : mb) : 0ULL;
            int kept = s_kept;
            int done = 0;
            for (int q = 0; q < CW && wbase + q < NW; ++q) {
                int w = wbase + q;
                unsigned long long live = ~__shfl(cm, q, 64);
                if (w == NW - 1) live &= (1ULL << 48) - 1;   // ranks >= 6000 dead
                unsigned long long kb = 0ULL;
                while (live) {
                    int b = __ffsll((unsigned long long)live) - 1;
                    unsigned long long rowb = __shfl(dg[q], b, 64);
                    kb |= 1ULL << b;
                    live &= ~(rowb | (1ULL << b));
                    kept++;
                    if (kept == POSTN) { done = 1; live = 0ULL; }
                }
                if (kb) {
                    if (lane == 0) {
                        unsigned long long t = kb;
                        int k0 = kept - __popcll(kb);
                        while (t) {
                            int b = __ffsll((unsigned long long)t) - 1; t &= t - 1;
                            keptArr[k0++] = (w << 6) + b;
                        }
                    }
                    if (done) break;
                    unsigned long long t = kb;
                    while (t) {
                        int b = __ffsll((unsigned long long)t) - 1; t &= t - 1;
                        unsigned long long rw = (lane < CW && lane > q)
                            ? cblk[(lane << 9) + (q << 6) + b] : 0ULL;
                        cm |= rw;
                    }
                }
                if (done) break;
            }
            if (lane == 0) { s_kept = kept; if (done) s_done = 1; }
        }
        __syncthreads();
        int keptNow = s_kept;
        bool fin = (s_done != 0) || (c == NCHUNK - 1);
        if (!fin) {
            if (tid >= 64) {
                // stage next chunk (waves 1-3)
                int wb2 = wbase + CW;
                int nw2 = NW - wb2; if (nw2 > CW) nw2 = CW;
                int rb2 = wb2 << 6;
                for (int e = tid - 64; e < CW * 512; e += 192) {
                    int q = e >> 9, r = e & 511;
                    cblk[e] = (q < nw2 && rb2 + r < NPADR)
                        ? diagw[((size_t)(wb2 + q) << 9) + r] : 0ULL;
                }
            } else {
                // propagate this chunk's kept rows into m0/m1 (wave 0, coalesced)
                for (int s = keptPrev; s < keptNow; ++s) {
                    size_t ro = (size_t)keptArr[s] * NW;
                    m0 |= rowr[ro + lane];
                    if (lane < NW - 64) m1 |= rowr[ro + 64 + lane];
                }
            }
        }
        keptPrev = keptNow;
        if (fin) break;
        __syncthreads();
    }
    __syncthreads();

    int kept = s_kept;
    for (int k = tid; k < POSTN; k += 256) {
        float4 bb = make_float4(0.f, 0.f, 0.f, 0.f);
        if (k < kept) bb = sortedbox[keptArr[k]];
        out[k * 5 + 0] = 0.0f;
        out[k * 5 + 1] = bb.x;
        out[k * 5 + 2] = bb.y;
        out[k * 5 + 3] = bb.z;
        out[k * 5 + 4] = bb.w;
    }
}

extern "C" void kernel_launch(void* const* d_in, const int* in_sizes, int n_in,
                              void* d_out, int out_size, void* d_ws, size_t ws_size,
                              hipStream_t stream) {
    const float* scores = (const float*)d_in[0];
    const float* deltas = (const float*)d_in[1];
    const float* iminfo = (const float*)d_in[2];
    char* w = (char*)d_ws;
    // workspace layout (~5.4 MB). rowr ALIASES boxes+skeys (both dead after rankscatter).
    float4*   boxes = (float4*)w;                                   // [0, 3538944)
    unsigned* skeys = (unsigned*)(w + 3538944);                     // [3538944, 4423680)
    unsigned long long* rowr = (unsigned long long*)w;              // [0, 4524032) alias
    unsigned* hist  = (unsigned*)(w + 4524032);                     // [4524032, 4786176)
    unsigned* meta  = (unsigned*)(w + 4786176);                     // 16 words
    unsigned long long* cbuf = (unsigned long long*)(w + 4786240);  // [4786240, 4851776)
    float4* sortedbox = (float4*)(w + 4851776);                     // [4851776, 4948032)
    unsigned long long* diagw = (unsigned long long*)(w + 4948096); // [4948096, 5333120)
    float* out = (float*)d_out;

    hipMemsetAsync(hist, 0, NBIN * sizeof(unsigned) + 64, stream);  // hist + meta
    decode_kernel<<<NCELL / 256, 256, 0, stream>>>(scores, deltas, iminfo, boxes, skeys, hist);
    thresh_kernel<<<1, 1024, 0, stream>>>(hist, meta);
    compact_kernel<<<(NTOT + 255) / 256, 256, 0, stream>>>(skeys, meta, cbuf);
    rankscatter_kernel<<<256, 256, 0, stream>>>(cbuf, meta, boxes, sortedbox);
    matrix_kernel<<<dim3(24, 94), 256, 0, stream>>>(sortedbox, rowr, diagw);
    scan_kernel<<<1, 256, 0, stream>>>(rowr, diagw, sortedbox, out);
}

// Round 8
// 227.722 us; speedup vs baseline: 2.2528x; 1.1741x over previous
//
#include <hip/hip_runtime.h>

#define NCELL 24576      // 128*192 feature cells
#define NTOT  221184     // NCELL * 9
#define NBIN13 8192      // 13-bit score-key histogram bins (LDS)
#define TOPN  6000
#define POSTN 300
#define CAP   8192       // compaction capacity
#define NPADR 6016       // padded candidate count (94 words of 64)
#define NW    94         // suppression-mask words per row
#define CW    8          // words per scan chunk (512 ranks)
#define NCHUNK 12        // ceil(94/8)

// ---------------- decode anchors + scores, build sort keys ----------------
__global__ void decode_kernel(const float* __restrict__ scores,
                              const float* __restrict__ deltas,
                              const float* __restrict__ iminfo,
                              float4* __restrict__ boxes,
                              unsigned* __restrict__ skeys) {
#pragma clang fp contract(off)
    int c = blockIdx.x * blockDim.x + threadIdx.x;
    if (c >= NCELL) return;
    const float AW[9] = {184.f,368.f,736.f,128.f,256.f,512.f, 88.f,176.f,352.f};
    const float AH[9] = { 96.f,192.f,384.f,128.f,256.f,512.f,176.f,352.f,704.f};
    float sx = (float)((c >> 7) << 4);   // (c/128)*16  -- 'ij' meshgrid quirk
    float sy = (float)((c & 127) << 4);  // (c%128)*16
    float imh = iminfo[0], imw = iminfo[1], ims = iminfo[2];
    float xhi = imw - 1.0f, yhi = imh - 1.0f;
    float ms = 16.0f * ims;
    float ctrx = sx + 8.0f, ctry = sy + 8.0f;
    const float* sbase = scores + 9 * NCELL + c;
    const float* dbase = deltas + c;
#pragma unroll
    for (int a = 0; a < 9; ++a) {
        float sc = sbase[a * NCELL];
        float dx = dbase[(4 * a + 0) * NCELL];
        float dy = dbase[(4 * a + 1) * NCELL];
        float dw = dbase[(4 * a + 2) * NCELL];
        float dh = dbase[(4 * a + 3) * NCELL];
        float pcx = dx * AW[a] + ctrx;
        float pcy = dy * AH[a] + ctry;
        float pw = expf(dw) * AW[a];
        float ph = expf(dh) * AH[a];
        float x1 = pcx - 0.5f * pw;
        float y1 = pcy - 0.5f * ph;
        float x2 = pcx + 0.5f * pw;
        float y2 = pcy + 0.5f * ph;
        x1 = fminf(fmaxf(x1, 0.0f), xhi);
        x2 = fminf(fmaxf(x2, 0.0f), xhi);
        y1 = fminf(fmaxf(y1, 0.0f), yhi);
        y2 = fminf(fmaxf(y2, 0.0f), yhi);
        bool valid = ((x2 - x1 + 1.0f) >= ms) && ((y2 - y1 + 1.0f) >= ms);
        unsigned u = __float_as_uint(sc);
        unsigned key = (u & 0x80000000u) ? ~u : (u | 0x80000000u);
        if (!valid) key = 0x007FFFFFu;   // sort key of -inf
        boxes[a * NCELL + c] = make_float4(x1, y1, x2, y2);
        skeys[a * NCELL + c] = key;
    }
}

// ---------------- LDS histogram + threshold bin T (13-bit) + zero meta ----------------
__global__ __launch_bounds__(1024) void thresh_kernel(const unsigned* __restrict__ skeys,
                                                      unsigned* __restrict__ meta) {
    __shared__ unsigned hist[NBIN13];      // 32 KB
    __shared__ unsigned psum[1024];
    __shared__ unsigned csum[256];
    __shared__ unsigned sB, sAbove;
    int tid = threadIdx.x;
    for (int b = tid; b < NBIN13; b += 1024) hist[b] = 0u;
    __syncthreads();
    const uint4* s4 = (const uint4*)skeys;
    for (int q = tid; q < NTOT / 4; q += 1024) {
        uint4 u = s4[q];
        atomicAdd(&hist[u.x >> 19], 1u);
        atomicAdd(&hist[u.y >> 19], 1u);
        atomicAdd(&hist[u.z >> 19], 1u);
        atomicAdd(&hist[u.w >> 19], 1u);
    }
    __syncthreads();
    // psum[t] = sum of 8 bins [t*8, t*8+8)
    unsigned s = 0;
#pragma unroll
    for (int q = 0; q < 8; ++q) s += hist[tid * 8 + q];
    psum[tid] = s;
    __syncthreads();
    if (tid < 256)
        csum[tid] = psum[tid * 4] + psum[tid * 4 + 1] + psum[tid * 4 + 2] + psum[tid * 4 + 3];
    __syncthreads();
    // coarse: 256 groups of 32 bins; find group with the top-6000 crossing
    if (tid < 64) {
        int lane = tid;
        unsigned c0 = csum[lane * 4 + 0], c1 = csum[lane * 4 + 1];
        unsigned c2 = csum[lane * 4 + 2], c3 = csum[lane * 4 + 3];
        unsigned ls = c0 + c1 + c2 + c3;
        unsigned v = ls;
#pragma unroll
        for (int o = 1; o < 64; o <<= 1) {
            unsigned t = __shfl_down(v, o, 64);
            if (lane + o < 64) v += t;
        }
        unsigned sufExcl = v - ls;   // count in groups above this lane's 4
        unsigned a3 = sufExcl;
        unsigned a2 = a3 + c3;
        unsigned a1 = a2 + c2;
        unsigned a0 = a1 + c1;
        if (a0 < TOPN && a0 + c0 >= TOPN) { sB = lane * 4 + 0; sAbove = a0; }
        if (a1 < TOPN && a1 + c1 >= TOPN) { sB = lane * 4 + 1; sAbove = a1; }
        if (a2 < TOPN && a2 + c2 >= TOPN) { sB = lane * 4 + 2; sAbove = a2; }
        if (a3 < TOPN && a3 + c3 >= TOPN) { sB = lane * 4 + 3; sAbove = a3; }
    }
    __syncthreads();
    // fine: 32 bins within group sB
    if (tid < 32) {
        unsigned B = sB, above = sAbove;
        unsigned h = hist[B * 32 + tid];
        unsigned v = h;
#pragma unroll
        for (int o = 1; o < 32; o <<= 1) {
            unsigned t = __shfl_down(v, o, 64);
            if (tid + o < 32) v += t;
        }
        unsigned sufExcl = v - h;
        unsigned ab = above + sufExcl;
        if (ab < TOPN && ab + h >= TOPN) meta[1] = B * 32 + tid;
    }
    if (tid == 0) meta[0] = 0u;   // compaction counter
}

// ---------------- compact all candidates with key_hi13 >= T ----------------
__global__ void compact_kernel(const unsigned* __restrict__ skeys,
                               unsigned* __restrict__ meta,
                               unsigned long long* __restrict__ cbuf) {
    int m = blockIdx.x * blockDim.x + threadIdx.x;
    if (m >= NTOT) return;
    unsigned T = meta[1];
    unsigned sk = skeys[m];
    if ((sk >> 19) >= T) {
        unsigned pos = atomicAdd(&meta[0], 1u);
        if (pos < CAP) {
            unsigned n = (unsigned)((m % NCELL) * 9 + (m / NCELL));  // original flat index
            cbuf[pos] = ((unsigned long long)sk << 32) | (unsigned long long)(~n);
        }
    }
}

// ---------------- rank by counting + scatter (atomic-free, no rank array) ----------------
__global__ __launch_bounds__(256) void rankscatter_kernel(const unsigned long long* __restrict__ cbuf,
                                                          const unsigned* __restrict__ meta,
                                                          const float4* __restrict__ boxes,
                                                          float4* __restrict__ sortedbox) {
    __shared__ unsigned long long jk[512];
    unsigned count = meta[0];
    if (count > (unsigned)CAP) count = CAP;
    int tid = threadIdx.x;
    int i = blockIdx.x * 32 + (tid >> 3);
    int slice = tid & 7;
    unsigned long long ki = (i < (int)count) ? cbuf[i] : ~0ULL;
    unsigned cr = 0;
    for (int jt = 0; jt < 16; ++jt) {
        if ((jt << 9) >= (int)count) break;    // uniform across block
        __syncthreads();
        for (int q = tid; q < 512; q += 256) {
            int j = (jt << 9) + q;
            jk[q] = (j < (int)count) ? cbuf[j] : 0ULL;   // 0 never > any real key
        }
        __syncthreads();
#pragma unroll 8
        for (int j = 0; j < 64; ++j) cr += (jk[slice + (j << 3)] > ki) ? 1u : 0u;
    }
    cr += __shfl_down(cr, 4, 8);
    cr += __shfl_down(cr, 2, 8);
    cr += __shfl_down(cr, 1, 8);
    if (slice == 0 && i < (int)count && cr < NPADR) {
        unsigned n = ~(unsigned)ki;
        unsigned m = (n % 9u) * (unsigned)NCELL + (n / 9u);
        sortedbox[cr] = boxes[m];
    }
}

// ---------------- all-pairs suppression matrix: word-per-thread ----------------
__global__ __launch_bounds__(256) void matrix_kernel(const float4* __restrict__ sortedbox,
                                                     unsigned long long* __restrict__ rowr,
                                                     unsigned long long* __restrict__ diagw) {
#pragma clang fp contract(off)
    __shared__ float4 jb[256];
    __shared__ float  ja[256];
    int tid = threadIdx.x;
    int lane = tid & 63, wave = tid >> 6;
    int i0 = blockIdx.y << 6;
    int i = i0 + lane;
    int w = (blockIdx.x << 2) + wave;
    int jbase = blockIdx.x << 8;
    unsigned long long word = 0ULL;

    if (jbase + 255 > i0) {                  // tile not entirely below diagonal
        int jg = jbase + tid;
        float4 v = (jg < NPADR) ? sortedbox[jg] : make_float4(0.f, 0.f, 0.f, 0.f);
        jb[tid] = v;
        ja[tid] = (v.z - v.x) * (v.w - v.y);
        __syncthreads();
        if (w < NW && ((w << 6) + 63) > i) { // this word has bits above the diagonal
            float4 bi = sortedbox[i];
            float ai = (bi.z - bi.x) * (bi.w - bi.y);
            int jl0 = wave << 6;
            int jg0 = (w << 6);
#pragma unroll 8
            for (int j = 0; j < 64; ++j) {
                float4 bj = jb[jl0 + j];
                float aj = ja[jl0 + j];
                float iw = fminf(bi.z, bj.z) - fmaxf(bi.x, bj.x);
                float ih = fminf(bi.w, bj.w) - fmaxf(bi.y, bj.y);
                iw = fmaxf(iw, 0.0f);
                ih = fmaxf(ih, 0.0f);
                float inter = iw * ih;
                float denom = fmaxf(ai + aj - inter, 1e-9f);
                bool sup = (jg0 + j > i) && (inter / denom > 0.7f);
                word |= (unsigned long long)sup << j;
            }
        }
    }
    if (w < NW) {
        rowr[(size_t)i * NW + w] = word;
        if ((i >> 9) == (w >> 3))            // block-diagonal word -> word-major copy
            diagw[((size_t)w << 9) + (i & 511)] = word;
    }
}

// ---------------- greedy scan: shfl resolve + MLP-batched propagate ----------------
__global__ __launch_bounds__(256) void scan_kernel(const unsigned long long* __restrict__ rowr,
                                                   const unsigned long long* __restrict__ diagw,
                                                   const float4* __restrict__ sortedbox,
                                                   float* __restrict__ out) {
    __shared__ unsigned long long cblk[CW * 512];   // 32 KB, word-major: cblk[q*512 + r]
    __shared__ unsigned long long gm[128];          // global suppression mask (94 used)
    __shared__ int keptArr[POSTN];
    __shared__ int s_kept;
    __shared__ int s_done;
    int tid = threadIdx.x;
    int lane = tid & 63, wave = tid >> 6;

    if (tid < 128) gm[tid] = (tid == 93) ? ~((1ULL << 48) - 1) : 0ULL; // ranks>=6000 dead
    if (tid == 0) { s_kept = 0; s_done = 0; }
    for (int e = tid; e < CW * 512; e += 256) cblk[e] = diagw[e];   // stage chunk 0
    __syncthreads();

    int keptPrev = 0;
    for (int c = 0; c < NCHUNK; ++c) {
        int wbase = c * CW;
        if (tid < 64) {
            unsigned long long dg[CW];
#pragma unroll
            for (int q = 0; q < CW; ++q) dg[q] = cblk[(q << 9) + (q << 6) + lane];
            unsigned long long cm = (lane < CW) ? gm[wbase + lane] : 0ULL;
            int kept = s_kept;
            int done = 0;
            for (int q = 0; q < CW && wbase + q < NW; ++q) {
                int w = wbase + q;
                unsigned long long live = ~__shfl(cm, q, 64);
                if (w == NW - 1) live &= (1ULL << 48) - 1;
                unsigned long long kb = 0ULL;
                while (live) {
                    int b = __ffsll((unsigned long long)live) - 1;
                    unsigned long long rowb = __shfl(dg[q], b, 64);
                    kb |= 1ULL << b;
                    live &= ~(rowb | (1ULL << b));
                    kept++;
                    if (kept == POSTN) { done = 1; live = 0ULL; }
                }
                if (kb) {
                    if (lane == 0) {
                        unsigned long long t = kb;
                        int k0 = kept - __popcll(kb);
                        while (t) {
                            int b = __ffsll((unsigned long long)t) - 1; t &= t - 1;
                            keptArr[k0++] = (w << 6) + b;
                        }
                    }
                    if (done) break;
                    unsigned long long t = kb;
                    while (t) {
                        int b = __ffsll((unsigned long long)t) - 1; t &= t - 1;
                        unsigned long long rw = (lane < CW && lane > q)
                            ? cblk[(lane << 9) + (q << 6) + b] : 0ULL;
                        cm |= rw;
                    }
                }
                if (done) break;
            }
            if (lane == 0) { s_kept = kept; if (done) s_done = 1; }
        }
        __syncthreads();
        int keptNow = s_kept;
        bool fin = (s_done != 0) || (c == NCHUNK - 1);
        if (!fin) {
            if (wave >= 2) {
                // stage next chunk (waves 2-3)
                int wb2 = wbase + CW;
                int nw2 = NW - wb2; if (nw2 > CW) nw2 = CW;
                int rb2 = wb2 << 6;
                for (int e = tid - 128; e < CW * 512; e += 128) {
                    int q = e >> 9, r = e & 511;
                    cblk[e] = (q < nw2 && rb2 + r < NPADR)
                        ? diagw[((size_t)(wb2 + q) << 9) + r] : 0ULL;
                }
            } else {
                // propagate kept rows into gm (waves 0-1, 4-row unroll -> 8 loads in flight)
                int hi = (lane < NW - 64);
                unsigned long long a0 = 0ULL, a1 = 0ULL;
                int s = keptPrev + wave;
                for (; s + 6 < keptNow; s += 8) {
                    size_t r0 = (size_t)keptArr[s] * NW;
                    size_t r1 = (size_t)keptArr[s + 2] * NW;
                    size_t r2 = (size_t)keptArr[s + 4] * NW;
                    size_t r3 = (size_t)keptArr[s + 6] * NW;
                    unsigned long long x0 = rowr[r0 + lane];
                    unsigned long long x1 = rowr[r1 + lane];
                    unsigned long long x2 = rowr[r2 + lane];
                    unsigned long long x3 = rowr[r3 + lane];
                    unsigned long long y0 = hi ? rowr[r0 + 64 + lane] : 0ULL;
                    unsigned long long y1 = hi ? rowr[r1 + 64 + lane] : 0ULL;
                    unsigned long long y2 = hi ? rowr[r2 + 64 + lane] : 0ULL;
                    unsigned long long y3 = hi ? rowr[r3 + 64 + lane] : 0ULL;
                    a0 |= x0 | x1 | x2 | x3;
                    a1 |= y0 | y1 | y2 | y3;
                }
                for (; s < keptNow; s += 2) {
                    size_t r0 = (size_t)keptArr[s] * NW;
                    a0 |= rowr[r0 + lane];
                    if (hi) a1 |= rowr[r0 + 64 + lane];
                }
                if (a0) atomicOr(&gm[lane], a0);
                if (a1) atomicOr(&gm[64 + lane], a1);
            }
        }
        keptPrev = keptNow;
        if (fin) break;
        __syncthreads();
    }
    __syncthreads();

    int kept = s_kept;
    for (int k = tid; k < POSTN; k += 256) {
        float4 bb = make_float4(0.f, 0.f, 0.f, 0.f);
        if (k < kept) bb = sortedbox[keptArr[k]];
        out[k * 5 + 0] = 0.0f;
        out[k * 5 + 1] = bb.x;
        out[k * 5 + 2] = bb.y;
        out[k * 5 + 3] = bb.z;
        out[k * 5 + 4] = bb.w;
    }
}

extern "C" void kernel_launch(void* const* d_in, const int* in_sizes, int n_in,
                              void* d_out, int out_size, void* d_ws, size_t ws_size,
                              hipStream_t stream) {
    const float* scores = (const float*)d_in[0];
    const float* deltas = (const float*)d_in[1];
    const float* iminfo = (const float*)d_in[2];
    char* w = (char*)d_ws;
    // workspace layout (~5.4 MB). rowr ALIASES boxes+skeys (both dead after rankscatter).
    float4*   boxes = (float4*)w;                                   // [0, 3538944)
    unsigned* skeys = (unsigned*)(w + 3538944);                     // [3538944, 4423680)
    unsigned long long* rowr = (unsigned long long*)w;              // [0, 4524032) alias
    unsigned* meta  = (unsigned*)(w + 4786176);                     // 16 words
    unsigned long long* cbuf = (unsigned long long*)(w + 4786240);  // [4786240, 4851776)
    float4* sortedbox = (float4*)(w + 4851776);                     // [4851776, 4948032)
    unsigned long long* diagw = (unsigned long long*)(w + 4948096); // [4948096, 5333120)
    float* out = (float*)d_out;

    decode_kernel<<<NCELL / 256, 256, 0, stream>>>(scores, deltas, iminfo, boxes, skeys);
    thresh_kernel<<<1, 1024, 0, stream>>>(skeys, meta);
    compact_kernel<<<(NTOT + 255) / 256, 256, 0, stream>>>(skeys, meta, cbuf);
    rankscatter_kernel<<<256, 256, 0, stream>>>(cbuf, meta, boxes, sortedbox);
    matrix_kernel<<<dim3(24, 94), 256, 0, stream>>>(sortedbox, rowr, diagw);
    scan_kernel<<<1, 256, 0, stream>>>(rowr, diagw, sortedbox, out);
}